// Round 5
// baseline (536.211 us; speedup 1.0000x reference)
//
#include <hip/hip_runtime.h>
#include <math.h>

// (B, L, E, H) = (4, 1024, 2048, 16), DH = 128
#define BB 4
#define LL 1024
#define EE 2048
#define HH 16
#define DHD 128
#define NTOK 4096
#define NBH 64
#define OUT0_ELEMS 8388608     // B*L*E

typedef __attribute__((ext_vector_type(8))) short short8;       // 8 bf16 (MFMA A/B frag)
typedef __attribute__((ext_vector_type(4))) float f32x4;        // MFMA C/D frag
typedef __attribute__((ext_vector_type(4))) unsigned short ushort4v;
typedef __attribute__((ext_vector_type(8))) unsigned short ushort8v;

__device__ __forceinline__ unsigned short f2bf(float x) {
    union { float f; unsigned int u; } v; v.f = x;
    unsigned int r = v.u + 0x7FFFu + ((v.u >> 16) & 1u);   // RNE
    return (unsigned short)(r >> 16);
}
__device__ __forceinline__ float bf2f(unsigned short h) {
    union { unsigned int u; float f; } v; v.u = ((unsigned int)h) << 16;
    return v.f;
}

// async global->LDS, 16B per lane
__device__ __forceinline__ void gload16(const void* g, void* l) {
    __builtin_amdgcn_global_load_lds((const __attribute__((address_space(1))) void*)g,
                                     (__attribute__((address_space(3))) void*)l,
                                     16, 0, 0);
}

// ---------------------------------------------------------------------------
// fp32 -> bf16 bulk convert
// ---------------------------------------------------------------------------
__global__ __launch_bounds__(256) void cvt_k(const float* __restrict__ in,
                                             unsigned short* __restrict__ out, int n) {
    int i = (blockIdx.x * 256 + threadIdx.x) * 8;
    if (i >= n) return;
    float4 a = *(const float4*)(in + i);
    float4 b = *(const float4*)(in + i + 4);
    ushort4v u, w;
    u.x = f2bf(a.x); u.y = f2bf(a.y); u.z = f2bf(a.z); u.w = f2bf(a.w);
    w.x = f2bf(b.x); w.y = f2bf(b.y); w.z = f2bf(b.z); w.w = f2bf(b.w);
    *(ushort4v*)(out + i) = u;
    *(ushort4v*)(out + i + 4) = w;
}

// ---------------------------------------------------------------------------
// xPos table
// ---------------------------------------------------------------------------
__global__ __launch_bounds__(64) void xpos_table_k(float4* __restrict__ tab) {
    int t = blockIdx.x;
    int j = threadIdx.x;
    float pos = (float)(t - 512);
    float base = (2.0f * (float)j + 51.2f) * (1.0f / 179.2f);
    float sc = powf(base, pos * (1.0f / 512.0f));
    float inv_freq = powf(10000.0f, -(float)j * (1.0f / 64.0f));
    float ang = (float)t * inv_freq;
    float s = sinf(ang);
    float c = cosf(ang);
    tab[(t << 6) | j] = make_float4(c * sc, s * sc, c / sc, s / sc);
}

// ---------------------------------------------------------------------------
// xPos rotate q / k in place, bf16 split layout (BH,L,DH)
// ---------------------------------------------------------------------------
__global__ __launch_bounds__(256) void xpos_apply_k(unsigned short* __restrict__ q,
                                                    unsigned short* __restrict__ k,
                                                    const float4* __restrict__ tab) {
    int g = blockIdx.x * 256 + threadIdx.x;   // 64*1024*16
    int jj = g & 15;
    int t = (g >> 4) & 1023;
    int bh = g >> 14;
    size_t off = (((size_t)((bh << 10) | t)) << 7) + jj * 8;
    ushort8v qv = *(const ushort8v*)(q + off);
    ushort8v kv = *(const ushort8v*)(k + off);
    ushort8v qo, ko;
#pragma unroll
    for (int p = 0; p < 4; ++p) {
        float4 tb = tab[(t << 6) | (jj * 4 + p)];
        float qx = bf2f(qv[2 * p]), qy = bf2f(qv[2 * p + 1]);
        float kx = bf2f(kv[2 * p]), ky = bf2f(kv[2 * p + 1]);
        qo[2 * p]     = f2bf(qx * tb.x - qy * tb.y);
        qo[2 * p + 1] = f2bf(qy * tb.x + qx * tb.y);
        ko[2 * p]     = f2bf(kx * tb.z - ky * tb.w);
        ko[2 * p + 1] = f2bf(ky * tb.z + kx * tb.w);
    }
    *(ushort8v*)(q + off) = qo;
    *(ushort8v*)(k + off) = ko;
}

// ---------------------------------------------------------------------------
// Combined QKV projection GEMM: C = X @ [Wq;Wk;Wv]^T, N = 6144.
// w = n>>11 selects q/k/v (block-uniform: 2048 % 128 == 0).
//   w=0 -> qb bf16 split (BH,L,DH), * scaling
//   w=1 -> kb bf16 split
//   w=2 -> vt bf16 transposed (BH,DH,L)
// ---------------------------------------------------------------------------
__global__ __launch_bounds__(256)
void mmqkv_k(const unsigned short* __restrict__ Abf, const unsigned short* __restrict__ Wqkv,
             const float* __restrict__ bq, const float* __restrict__ bk,
             const float* __restrict__ bv, unsigned short* __restrict__ qb,
             unsigned short* __restrict__ kb, unsigned short* __restrict__ vt,
             float scaling) {
    __shared__ alignas(16) unsigned short lA[128 * 32];
    __shared__ alignas(16) unsigned short lB[128 * 32];

    const int tid = threadIdx.x;
    const int lane = tid & 63;
    const int wave = tid >> 6;
    const int wr = wave >> 1, wc = wave & 1;
    const int fr = lane & 15, fq = lane >> 4;
    const int m0 = blockIdx.y * 128, n0 = blockIdx.x * 128;
    const int w = n0 >> 11;                       // 0=q, 1=k, 2=v
    const float* bsel = (w == 0) ? bq : (w == 1) ? bk : bv;
    const float alpha = (w == 0) ? scaling : 1.0f;

    f32x4 acc[4][4];
#pragma unroll
    for (int i = 0; i < 4; ++i)
#pragma unroll
        for (int j = 0; j < 4; ++j) acc[i][j] = (f32x4){0.f, 0.f, 0.f, 0.f};

    for (int k0 = 0; k0 < 2048; k0 += 32) {
#pragma unroll
        for (int i = 0; i < 2; ++i) {
            int c = i * 256 + tid;
            int r = c >> 2, kc = c & 3;
            gload16(Abf + (size_t)(m0 + r) * 2048 + k0 + kc * 8, &lA[c * 8]);
        }
#pragma unroll
        for (int i = 0; i < 2; ++i) {
            int c = i * 256 + tid;
            int r = c >> 2, kc = c & 3;
            gload16(Wqkv + (size_t)(n0 + r) * 2048 + k0 + kc * 8, &lB[c * 8]);
        }
        __syncthreads();

        short8 afr[4], bfr[4];
#pragma unroll
        for (int mi = 0; mi < 4; ++mi)
            afr[mi] = *(const short8*)&lA[(wr * 64 + mi * 16 + fr) * 32 + fq * 8];
#pragma unroll
        for (int ni = 0; ni < 4; ++ni)
            bfr[ni] = *(const short8*)&lB[(wc * 64 + ni * 16 + fr) * 32 + fq * 8];
#pragma unroll
        for (int mi = 0; mi < 4; ++mi)
#pragma unroll
            for (int ni = 0; ni < 4; ++ni)
                acc[mi][ni] = __builtin_amdgcn_mfma_f32_16x16x32_bf16(
                    afr[mi], bfr[ni], acc[mi][ni], 0, 0, 0);
        __syncthreads();
    }

#pragma unroll
    for (int mi = 0; mi < 4; ++mi) {
#pragma unroll
        for (int ni = 0; ni < 4; ++ni) {
#pragma unroll
            for (int r = 0; r < 4; ++r) {
                int m = m0 + wr * 64 + mi * 16 + fq * 4 + r;
                int n = n0 + wc * 64 + ni * 16 + fr;
                int nn = n & 2047;
                int b_ = m >> 10, t = m & 1023, h = nn >> 7, d = nn & 127;
                float v = alpha * (acc[mi][ni][r] + bsel[nn]);
                if (w == 0)
                    qb[(((size_t)(b_ * HH + h) << 10 | t) << 7) | d] = f2bf(v);
                else if (w == 1)
                    kb[(((size_t)(b_ * HH + h) << 10 | t) << 7) | d] = f2bf(v);
                else
                    vt[((size_t)((b_ * HH + h) * 128 + d) << 10) | t] = f2bf(v);
            }
        }
    }
}

// ---------------------------------------------------------------------------
// Output projection GEMM: out = am @ Wo^T + bo, fp32 (B,L,E)
// ---------------------------------------------------------------------------
__global__ __launch_bounds__(256)
void mmo_k(const unsigned short* __restrict__ Abf, const unsigned short* __restrict__ Bp,
           const float* __restrict__ bias, float* __restrict__ C) {
    __shared__ alignas(16) unsigned short lA[128 * 32];
    __shared__ alignas(16) unsigned short lB[128 * 32];

    const int tid = threadIdx.x;
    const int lane = tid & 63;
    const int wave = tid >> 6;
    const int wr = wave >> 1, wc = wave & 1;
    const int fr = lane & 15, fq = lane >> 4;
    const int m0 = blockIdx.y * 128, n0 = blockIdx.x * 128;

    f32x4 acc[4][4];
#pragma unroll
    for (int i = 0; i < 4; ++i)
#pragma unroll
        for (int j = 0; j < 4; ++j) acc[i][j] = (f32x4){0.f, 0.f, 0.f, 0.f};

    for (int k0 = 0; k0 < 2048; k0 += 32) {
#pragma unroll
        for (int i = 0; i < 2; ++i) {
            int c = i * 256 + tid;
            int r = c >> 2, kc = c & 3;
            gload16(Abf + (size_t)(m0 + r) * 2048 + k0 + kc * 8, &lA[c * 8]);
        }
#pragma unroll
        for (int i = 0; i < 2; ++i) {
            int c = i * 256 + tid;
            int r = c >> 2, kc = c & 3;
            gload16(Bp + (size_t)(n0 + r) * 2048 + k0 + kc * 8, &lB[c * 8]);
        }
        __syncthreads();

        short8 afr[4], bfr[4];
#pragma unroll
        for (int mi = 0; mi < 4; ++mi)
            afr[mi] = *(const short8*)&lA[(wr * 64 + mi * 16 + fr) * 32 + fq * 8];
#pragma unroll
        for (int ni = 0; ni < 4; ++ni)
            bfr[ni] = *(const short8*)&lB[(wc * 64 + ni * 16 + fr) * 32 + fq * 8];
#pragma unroll
        for (int mi = 0; mi < 4; ++mi)
#pragma unroll
            for (int ni = 0; ni < 4; ++ni)
                acc[mi][ni] = __builtin_amdgcn_mfma_f32_16x16x32_bf16(
                    afr[mi], bfr[ni], acc[mi][ni], 0, 0, 0);
        __syncthreads();
    }

#pragma unroll
    for (int mi = 0; mi < 4; ++mi)
#pragma unroll
        for (int ni = 0; ni < 4; ++ni)
#pragma unroll
            for (int r = 0; r < 4; ++r) {
                int m = m0 + wr * 64 + mi * 16 + fq * 4 + r;
                int n = n0 + wc * 64 + ni * 16 + fr;
                C[(size_t)m * EE + n] = acc[mi][ni][r] + bias[n];
            }
}

// ---------------------------------------------------------------------------
// scores_k: one block per causal 128x128 tile (t-tile tt, s-tile ss<=tt, bh).
// S = q@k^T (K=128 MFMA), slab-transposed epilogue:
//   e = exp(S + rel - 15)   (causal-masked on diagonal tiles)
// e written fp32 (unnormalized) into the attn region of d_out; per-row
// partial sums into psum[bh][t][ss]. All global epilogue I/O is float4.
// ---------------------------------------------------------------------------
__global__ __launch_bounds__(256)
void scores_k(const unsigned short* __restrict__ qb, const unsigned short* __restrict__ kb,
              const float* __restrict__ rel, float* __restrict__ attnP,
              float* __restrict__ psum) {
    __shared__ alignas(16) char smem[16384];
    unsigned short* lA = (unsigned short*)smem;           // 128x32 bf16
    unsigned short* lB = (unsigned short*)(smem + 8192);  // 128x32 bf16
    float* slab = (float*)smem;                           // 32x128 f32 (epilogue reuse)

    const int tid = threadIdx.x;
    const int lane = tid & 63, wave = tid >> 6;
    const int wr = wave >> 1, wc = wave & 1;
    const int fr = lane & 15, fq = lane >> 4;

    int idx = blockIdx.x;                  // 0..35 triangular
    int tt = (int)((sqrtf(8.f * (float)idx + 1.f) - 1.f) * 0.5f);
    while ((tt + 1) * (tt + 2) / 2 <= idx) ++tt;
    while (tt * (tt + 1) / 2 > idx) --tt;
    const int ss = idx - tt * (tt + 1) / 2;
    const int t0 = tt << 7, s0 = ss << 7;
    const int bh = blockIdx.y;
    const int hh = bh & 15, bb = bh >> 4;

    const unsigned short* Q = qb + ((size_t)bh << 17);
    const unsigned short* K = kb + ((size_t)bh << 17);

    f32x4 acc[4][4];
#pragma unroll
    for (int i = 0; i < 4; ++i)
#pragma unroll
        for (int j = 0; j < 4; ++j) acc[i][j] = (f32x4){0.f, 0.f, 0.f, 0.f};

    for (int k0 = 0; k0 < 128; k0 += 32) {
#pragma unroll
        for (int i = 0; i < 2; ++i) {
            int c = i * 256 + tid;
            int r = c >> 2, kc = c & 3;
            gload16(Q + (size_t)(t0 + r) * 128 + k0 + kc * 8, &lA[c * 8]);
        }
#pragma unroll
        for (int i = 0; i < 2; ++i) {
            int c = i * 256 + tid;
            int r = c >> 2, kc = c & 3;
            gload16(K + (size_t)(s0 + r) * 128 + k0 + kc * 8, &lB[c * 8]);
        }
        __syncthreads();

        short8 afr[4], bfr[4];
#pragma unroll
        for (int mi = 0; mi < 4; ++mi)
            afr[mi] = *(const short8*)&lA[(wr * 64 + mi * 16 + fr) * 32 + fq * 8];
#pragma unroll
        for (int ni = 0; ni < 4; ++ni)
            bfr[ni] = *(const short8*)&lB[(wc * 64 + ni * 16 + fr) * 32 + fq * 8];
#pragma unroll
        for (int mi = 0; mi < 4; ++mi)
#pragma unroll
            for (int ni = 0; ni < 4; ++ni)
                acc[mi][ni] = __builtin_amdgcn_mfma_f32_16x16x32_bf16(
                    afr[mi], bfr[ni], acc[mi][ni], 0, 0, 0);
        __syncthreads();
    }

    // ---- slab-transposed epilogue: 4 slabs of 32 rows ----
    float* PO = attnP + (((size_t)(hh * BB + bb)) << 20);
    const float* RLb = rel + ((size_t)bh << 20);
#pragma unroll
    for (int sl = 0; sl < 4; ++sl) {
        if (wr == (sl >> 1)) {
#pragma unroll
            for (int mi2 = 0; mi2 < 2; ++mi2) {
                int mi = ((sl & 1) << 1) + mi2;
#pragma unroll
                for (int ni = 0; ni < 4; ++ni)
#pragma unroll
                    for (int r = 0; r < 4; ++r) {
                        int srow = (mi2 << 4) + (fq << 2) + r;
                        int col = (wc << 6) + (ni << 4) + fr;
                        slab[srow * 128 + (col ^ (((srow >> 2) & 3) << 4))] = acc[mi][ni][r];
                    }
            }
        }
        __syncthreads();
        {
            int srow = tid >> 3;
            int tg = t0 + (sl << 5) + srow;
            const float* RL = RLb + ((size_t)tg << 10) + s0;
            float* PR = PO + ((size_t)tg << 10) + s0;
            float rsum = 0.f;
#pragma unroll
            for (int c = 0; c < 4; ++c) {
                int col = ((tid & 7) << 2) + (c << 5);   // 8 lanes cover 128B contiguous
                float4 sv = *(const float4*)&slab[srow * 128 + (col ^ (((srow >> 2) & 3) << 4))];
                float4 rl = *(const float4*)(RL + col);
                float4 e;
                e.x = (s0 + col     <= tg) ? __expf(sv.x + rl.x - 15.f) : 0.f;
                e.y = (s0 + col + 1 <= tg) ? __expf(sv.y + rl.y - 15.f) : 0.f;
                e.z = (s0 + col + 2 <= tg) ? __expf(sv.z + rl.z - 15.f) : 0.f;
                e.w = (s0 + col + 3 <= tg) ? __expf(sv.w + rl.w - 15.f) : 0.f;
                *(float4*)(PR + col) = e;
                rsum += e.x + e.y + e.z + e.w;
            }
            rsum += __shfl_xor(rsum, 1);
            rsum += __shfl_xor(rsum, 2);
            rsum += __shfl_xor(rsum, 4);
            if ((tid & 7) == 0)
                psum[((((size_t)bh << 10) + tg) << 3) + ss] = rsum;
        }
        __syncthreads();
    }
}

// ---------------------------------------------------------------------------
// pv_k: per (t-tile, bh):
//   inv = 1/l from psum; staging loop reads e (fp32), writes back P = e*inv
//   (final output values) in place, converts P to bf16 LDS; O = P @ V via
//   MFMA; zero-fills s in [kend, 1024). One pass over the attn region.
// ---------------------------------------------------------------------------
__global__ __launch_bounds__(256)
void pv_k(float* __restrict__ attnP, const unsigned short* __restrict__ vt,
          const float* __restrict__ psum, unsigned short* __restrict__ am) {
    __shared__ alignas(16) unsigned short lA[128 * 32];
    __shared__ alignas(16) unsigned short lB[128 * 32];
    __shared__ float lInv[128];

    const int tid = threadIdx.x;
    const int lane = tid & 63, wave = tid >> 6;
    const int wr = wave >> 1, wc = wave & 1;
    const int fr = lane & 15, fq = lane >> 4;
    const int tt = 7 - blockIdx.x;       // heavy first
    const int t0 = tt << 7;
    const int bh = blockIdx.y;
    const int hh = bh & 15, bb = bh >> 4;

    float* PO = attnP + (((size_t)(hh * BB + bb)) << 20) + ((size_t)t0 << 10);
    const unsigned short* Vb = vt + ((size_t)bh << 17);

    if (tid < 128) {
        const float* p = psum + ((((size_t)bh << 10) + t0 + tid) << 3);
        float s = 0.f;
#pragma unroll
        for (int j = 0; j < 8; ++j) s += (j <= tt) ? p[j] : 0.f;
        lInv[tid] = 1.f / s;
    }
    __syncthreads();

    f32x4 acc[4][4];
#pragma unroll
    for (int i = 0; i < 4; ++i)
#pragma unroll
        for (int j = 0; j < 4; ++j) acc[i][j] = (f32x4){0.f, 0.f, 0.f, 0.f};

    const int kend = (tt + 1) << 7;
    for (int k0 = 0; k0 < kend; k0 += 32) {
#pragma unroll
        for (int i = 0; i < 4; ++i) {    // stage P 128x32: normalize, writeback, ->bf16
            int c = i * 256 + tid;
            int r = c >> 3, cc = c & 7;
            float* gp = PO + (size_t)r * 1024 + k0 + cc * 4;
            float4 v = *(const float4*)gp;
            float inv = lInv[r];
            v.x *= inv; v.y *= inv; v.z *= inv; v.w *= inv;
            *(float4*)gp = v;
            ushort4v h;
            h.x = f2bf(v.x); h.y = f2bf(v.y); h.z = f2bf(v.z); h.w = f2bf(v.w);
            *(ushort4v*)&lA[r * 32 + cc * 4] = h;
        }
#pragma unroll
        for (int i = 0; i < 2; ++i) {    // stage V^T 128x32
            int c = i * 256 + tid;
            int r = c >> 2, kc = c & 3;
            gload16(Vb + (size_t)r * 1024 + k0 + kc * 8, &lB[c * 8]);
        }
        __syncthreads();

        short8 afr[4], bfr[4];
#pragma unroll
        for (int mi = 0; mi < 4; ++mi)
            afr[mi] = *(const short8*)&lA[(wr * 64 + mi * 16 + fr) * 32 + fq * 8];
#pragma unroll
        for (int ni = 0; ni < 4; ++ni)
            bfr[ni] = *(const short8*)&lB[(wc * 64 + ni * 16 + fr) * 32 + fq * 8];
#pragma unroll
        for (int mi = 0; mi < 4; ++mi)
#pragma unroll
            for (int ni = 0; ni < 4; ++ni)
                acc[mi][ni] = __builtin_amdgcn_mfma_f32_16x16x32_bf16(
                    afr[mi], bfr[ni], acc[mi][ni], 0, 0, 0);
        __syncthreads();
    }

    // O epilogue (P already normalized -> acc is final O)
#pragma unroll
    for (int mi = 0; mi < 4; ++mi)
#pragma unroll
        for (int ni = 0; ni < 4; ++ni)
#pragma unroll
            for (int r = 0; r < 4; ++r) {
                int tl = wr * 64 + mi * 16 + fq * 4 + r;
                int d = wc * 64 + ni * 16 + fr;
                am[(((size_t)(bb * 1024 + t0 + tl)) << 11) + hh * 128 + d] =
                    f2bf(acc[mi][ni][r]);
            }

    // zero-fill s in [kend, 1024) for this block's 128 rows (wave per row)
    if (kend < 1024) {
        float4 z = make_float4(0.f, 0.f, 0.f, 0.f);
        for (int rr = wave; rr < 128; rr += 4)
            for (int c = kend + lane * 4; c < 1024; c += 256)
                *(float4*)(PO + (size_t)rr * 1024 + c) = z;
    }
}

// ---------------------------------------------------------------------------
extern "C" void kernel_launch(void* const* d_in, const int* in_sizes, int n_in,
                              void* d_out, int out_size, void* d_ws, size_t ws_size,
                              hipStream_t stream) {
    const float* query = (const float*)d_in[0];
    const float* Wq    = (const float*)d_in[1];
    const float* bq    = (const float*)d_in[2];
    const float* Wk    = (const float*)d_in[3];
    const float* bk    = (const float*)d_in[4];
    const float* Wv    = (const float*)d_in[5];
    const float* bv    = (const float*)d_in[6];
    const float* Wo    = (const float*)d_in[7];
    const float* bo    = (const float*)d_in[8];
    const float* rel   = (const float*)d_in[10];

    float* out    = (float*)d_out;              // (B, L, E)
    float* attn_w = out + OUT0_ELEMS;           // (H, B, L, L)

    char* w = (char*)d_ws;
    unsigned short* Xbf   = (unsigned short*)(w);               // 16MB  (B*L, E)
    unsigned short* Wqkvb = (unsigned short*)(w + (16 << 20));  // 24MB  (3*E, E)
    unsigned short* Wob   = (unsigned short*)(w + (40 << 20));  // 8MB
    unsigned short* qb    = (unsigned short*)(w + (48 << 20));  // 16MB (BH,L,DH)
    unsigned short* kb    = (unsigned short*)(w + (64 << 20));  // 16MB
    unsigned short* vt    = (unsigned short*)(w + (80 << 20));  // 16MB (BH,DH,L)
    unsigned short* am    = (unsigned short*)(w + (96 << 20));  // 16MB (B,L,E)
    float4* tab           = (float4*)(w + (112 << 20));         // 1MB
    float* psum           = (float*)(w + (113u << 20));         // 2MB (BH,L,8)

    const float scaling = 0.08838834764831845f; // DH^-0.5

    xpos_table_k<<<LL, 64, 0, stream>>>(tab);

    cvt_k<<<4096, 256, 0, stream>>>(query, Xbf, OUT0_ELEMS);
    cvt_k<<<2048, 256, 0, stream>>>(Wq, Wqkvb, EE * EE);
    cvt_k<<<2048, 256, 0, stream>>>(Wk, Wqkvb + (size_t)EE * EE, EE * EE);
    cvt_k<<<2048, 256, 0, stream>>>(Wv, Wqkvb + 2 * (size_t)EE * EE, EE * EE);
    cvt_k<<<2048, 256, 0, stream>>>(Wo, Wob, EE * EE);

    dim3 gqkv(3 * EE / 128, NTOK / 128);        // (48, 32)
    mmqkv_k<<<gqkv, 256, 0, stream>>>(Xbf, Wqkvb, bq, bk, bv, qb, kb, vt, scaling);

    xpos_apply_k<<<(NBH * LL * 16) / 256, 256, 0, stream>>>(qb, kb, tab);

    dim3 gsc(36, NBH);                          // causal tiles only
    scores_k<<<gsc, 256, 0, stream>>>(qb, kb, rel, attn_w, psum);

    dim3 gpv(8, NBH);
    pv_k<<<gpv, 256, 0, stream>>>(attn_w, vt, psum, am);

    dim3 gout(EE / 128, NTOK / 128);            // (16, 32)
    mmo_k<<<gout, 256, 0, stream>>>(am, Wob, bo, out);
}

// Round 6
// 481.522 us; speedup vs baseline: 1.1136x; 1.1136x over previous
//
#include <hip/hip_runtime.h>
#include <math.h>

// (B, L, E, H) = (4, 1024, 2048, 16), DH = 128
#define BB 4
#define LL 1024
#define EE 2048
#define HH 16
#define DHD 128
#define NTOK 4096
#define NBH 64
#define OUT0_ELEMS 8388608     // B*L*E

typedef __attribute__((ext_vector_type(8))) short short8;       // 8 bf16 (MFMA A/B frag)
typedef __attribute__((ext_vector_type(4))) float f32x4;        // MFMA C/D frag
typedef __attribute__((ext_vector_type(4))) unsigned short ushort4v;
typedef __attribute__((ext_vector_type(8))) unsigned short ushort8v;

__device__ __forceinline__ unsigned short f2bf(float x) {
    union { float f; unsigned int u; } v; v.f = x;
    unsigned int r = v.u + 0x7FFFu + ((v.u >> 16) & 1u);   // RNE
    return (unsigned short)(r >> 16);
}
__device__ __forceinline__ float bf2f(unsigned short h) {
    union { unsigned int u; float f; } v; v.u = ((unsigned int)h) << 16;
    return v.f;
}

// async global->LDS, 16B per lane
__device__ __forceinline__ void gload16(const void* g, void* l) {
    __builtin_amdgcn_global_load_lds((const __attribute__((address_space(1))) void*)g,
                                     (__attribute__((address_space(3))) void*)l,
                                     16, 0, 0);
}

// ---------------------------------------------------------------------------
// fp32 -> bf16 bulk convert
// ---------------------------------------------------------------------------
__global__ __launch_bounds__(256) void cvt_k(const float* __restrict__ in,
                                             unsigned short* __restrict__ out, int n) {
    int i = (blockIdx.x * 256 + threadIdx.x) * 8;
    if (i >= n) return;
    float4 a = *(const float4*)(in + i);
    float4 b = *(const float4*)(in + i + 4);
    ushort4v u, w;
    u.x = f2bf(a.x); u.y = f2bf(a.y); u.z = f2bf(a.z); u.w = f2bf(a.w);
    w.x = f2bf(b.x); w.y = f2bf(b.y); w.z = f2bf(b.z); w.w = f2bf(b.w);
    *(ushort4v*)(out + i) = u;
    *(ushort4v*)(out + i + 4) = w;
}

// ---------------------------------------------------------------------------
// xPos table
// ---------------------------------------------------------------------------
__global__ __launch_bounds__(64) void xpos_table_k(float4* __restrict__ tab) {
    int t = blockIdx.x;
    int j = threadIdx.x;
    float pos = (float)(t - 512);
    float base = (2.0f * (float)j + 51.2f) * (1.0f / 179.2f);
    float sc = powf(base, pos * (1.0f / 512.0f));
    float inv_freq = powf(10000.0f, -(float)j * (1.0f / 64.0f));
    float ang = (float)t * inv_freq;
    float s = sinf(ang);
    float c = cosf(ang);
    tab[(t << 6) | j] = make_float4(c * sc, s * sc, c / sc, s / sc);
}

// ---------------------------------------------------------------------------
// xPos rotate q / k in place, bf16 split layout (BH,L,DH)
// ---------------------------------------------------------------------------
__global__ __launch_bounds__(256) void xpos_apply_k(unsigned short* __restrict__ q,
                                                    unsigned short* __restrict__ k,
                                                    const float4* __restrict__ tab) {
    int g = blockIdx.x * 256 + threadIdx.x;   // 64*1024*16
    int jj = g & 15;
    int t = (g >> 4) & 1023;
    int bh = g >> 14;
    size_t off = (((size_t)((bh << 10) | t)) << 7) + jj * 8;
    ushort8v qv = *(const ushort8v*)(q + off);
    ushort8v kv = *(const ushort8v*)(k + off);
    ushort8v qo, ko;
#pragma unroll
    for (int p = 0; p < 4; ++p) {
        float4 tb = tab[(t << 6) | (jj * 4 + p)];
        float qx = bf2f(qv[2 * p]), qy = bf2f(qv[2 * p + 1]);
        float kx = bf2f(kv[2 * p]), ky = bf2f(kv[2 * p + 1]);
        qo[2 * p]     = f2bf(qx * tb.x - qy * tb.y);
        qo[2 * p + 1] = f2bf(qy * tb.x + qx * tb.y);
        ko[2 * p]     = f2bf(kx * tb.z - ky * tb.w);
        ko[2 * p + 1] = f2bf(ky * tb.z + kx * tb.w);
    }
    *(ushort8v*)(q + off) = qo;
    *(ushort8v*)(k + off) = ko;
}

// ---------------------------------------------------------------------------
// Combined QKV projection GEMM: C = X @ [Wq;Wk;Wv]^T, N = 6144.
// ---------------------------------------------------------------------------
__global__ __launch_bounds__(256)
void mmqkv_k(const unsigned short* __restrict__ Abf, const unsigned short* __restrict__ Wqkv,
             const float* __restrict__ bq, const float* __restrict__ bk,
             const float* __restrict__ bv, unsigned short* __restrict__ qb,
             unsigned short* __restrict__ kb, unsigned short* __restrict__ vt,
             float scaling) {
    __shared__ alignas(16) unsigned short lA[128 * 32];
    __shared__ alignas(16) unsigned short lB[128 * 32];

    const int tid = threadIdx.x;
    const int lane = tid & 63;
    const int wave = tid >> 6;
    const int wr = wave >> 1, wc = wave & 1;
    const int fr = lane & 15, fq = lane >> 4;
    const int m0 = blockIdx.y * 128, n0 = blockIdx.x * 128;
    const int w = n0 >> 11;                       // 0=q, 1=k, 2=v
    const float* bsel = (w == 0) ? bq : (w == 1) ? bk : bv;
    const float alpha = (w == 0) ? scaling : 1.0f;

    f32x4 acc[4][4];
#pragma unroll
    for (int i = 0; i < 4; ++i)
#pragma unroll
        for (int j = 0; j < 4; ++j) acc[i][j] = (f32x4){0.f, 0.f, 0.f, 0.f};

    for (int k0 = 0; k0 < 2048; k0 += 32) {
#pragma unroll
        for (int i = 0; i < 2; ++i) {
            int c = i * 256 + tid;
            int r = c >> 2, kc = c & 3;
            gload16(Abf + (size_t)(m0 + r) * 2048 + k0 + kc * 8, &lA[c * 8]);
        }
#pragma unroll
        for (int i = 0; i < 2; ++i) {
            int c = i * 256 + tid;
            int r = c >> 2, kc = c & 3;
            gload16(Wqkv + (size_t)(n0 + r) * 2048 + k0 + kc * 8, &lB[c * 8]);
        }
        __syncthreads();

        short8 afr[4], bfr[4];
#pragma unroll
        for (int mi = 0; mi < 4; ++mi)
            afr[mi] = *(const short8*)&lA[(wr * 64 + mi * 16 + fr) * 32 + fq * 8];
#pragma unroll
        for (int ni = 0; ni < 4; ++ni)
            bfr[ni] = *(const short8*)&lB[(wc * 64 + ni * 16 + fr) * 32 + fq * 8];
#pragma unroll
        for (int mi = 0; mi < 4; ++mi)
#pragma unroll
            for (int ni = 0; ni < 4; ++ni)
                acc[mi][ni] = __builtin_amdgcn_mfma_f32_16x16x32_bf16(
                    afr[mi], bfr[ni], acc[mi][ni], 0, 0, 0);
        __syncthreads();
    }

#pragma unroll
    for (int mi = 0; mi < 4; ++mi) {
#pragma unroll
        for (int ni = 0; ni < 4; ++ni) {
#pragma unroll
            for (int r = 0; r < 4; ++r) {
                int m = m0 + wr * 64 + mi * 16 + fq * 4 + r;
                int n = n0 + wc * 64 + ni * 16 + fr;
                int nn = n & 2047;
                int b_ = m >> 10, t = m & 1023, h = nn >> 7, d = nn & 127;
                float v = alpha * (acc[mi][ni][r] + bsel[nn]);
                if (w == 0)
                    qb[(((size_t)(b_ * HH + h) << 10 | t) << 7) | d] = f2bf(v);
                else if (w == 1)
                    kb[(((size_t)(b_ * HH + h) << 10 | t) << 7) | d] = f2bf(v);
                else
                    vt[((size_t)((b_ * HH + h) * 128 + d) << 10) | t] = f2bf(v);
            }
        }
    }
}

// ---------------------------------------------------------------------------
// Output projection GEMM: out = am @ Wo^T + bo, fp32 (B,L,E)
// ---------------------------------------------------------------------------
__global__ __launch_bounds__(256)
void mmo_k(const unsigned short* __restrict__ Abf, const unsigned short* __restrict__ Bp,
           const float* __restrict__ bias, float* __restrict__ C) {
    __shared__ alignas(16) unsigned short lA[128 * 32];
    __shared__ alignas(16) unsigned short lB[128 * 32];

    const int tid = threadIdx.x;
    const int lane = tid & 63;
    const int wave = tid >> 6;
    const int wr = wave >> 1, wc = wave & 1;
    const int fr = lane & 15, fq = lane >> 4;
    const int m0 = blockIdx.y * 128, n0 = blockIdx.x * 128;

    f32x4 acc[4][4];
#pragma unroll
    for (int i = 0; i < 4; ++i)
#pragma unroll
        for (int j = 0; j < 4; ++j) acc[i][j] = (f32x4){0.f, 0.f, 0.f, 0.f};

    for (int k0 = 0; k0 < 2048; k0 += 32) {
#pragma unroll
        for (int i = 0; i < 2; ++i) {
            int c = i * 256 + tid;
            int r = c >> 2, kc = c & 3;
            gload16(Abf + (size_t)(m0 + r) * 2048 + k0 + kc * 8, &lA[c * 8]);
        }
#pragma unroll
        for (int i = 0; i < 2; ++i) {
            int c = i * 256 + tid;
            int r = c >> 2, kc = c & 3;
            gload16(Bp + (size_t)(n0 + r) * 2048 + k0 + kc * 8, &lB[c * 8]);
        }
        __syncthreads();

        short8 afr[4], bfr[4];
#pragma unroll
        for (int mi = 0; mi < 4; ++mi)
            afr[mi] = *(const short8*)&lA[(wr * 64 + mi * 16 + fr) * 32 + fq * 8];
#pragma unroll
        for (int ni = 0; ni < 4; ++ni)
            bfr[ni] = *(const short8*)&lB[(wc * 64 + ni * 16 + fr) * 32 + fq * 8];
#pragma unroll
        for (int mi = 0; mi < 4; ++mi)
#pragma unroll
            for (int ni = 0; ni < 4; ++ni)
                acc[mi][ni] = __builtin_amdgcn_mfma_f32_16x16x32_bf16(
                    afr[mi], bfr[ni], acc[mi][ni], 0, 0, 0);
        __syncthreads();
    }

#pragma unroll
    for (int mi = 0; mi < 4; ++mi)
#pragma unroll
        for (int ni = 0; ni < 4; ++ni)
#pragma unroll
            for (int r = 0; r < 4; ++r) {
                int m = m0 + wr * 64 + mi * 16 + fq * 4 + r;
                int n = n0 + wc * 64 + ni * 16 + fr;
                C[(size_t)m * EE + n] = acc[mi][ni][r] + bias[n];
            }
}

// ---------------------------------------------------------------------------
// scores_k: one block per causal 128x128 tile (tt, ss<=tt, bh).
// S = q@k^T (K=128 MFMA), slab-transposed epilogue:
//   e = exp(S + rel - 15)   (causal-masked)
// e written BF16 (unnormalized) into ws ebuf[bh][t][s]; per-row partial
// sums into psum[bh][t][ss]. Epilogue I/O coalesced.
// ---------------------------------------------------------------------------
__global__ __launch_bounds__(256)
void scores_k(const unsigned short* __restrict__ qb, const unsigned short* __restrict__ kb,
              const float* __restrict__ rel, unsigned short* __restrict__ ebuf,
              float* __restrict__ psum) {
    __shared__ alignas(16) char smem[16384];
    unsigned short* lA = (unsigned short*)smem;           // 128x32 bf16
    unsigned short* lB = (unsigned short*)(smem + 8192);  // 128x32 bf16
    float* slab = (float*)smem;                           // 32x128 f32 (epilogue reuse)

    const int tid = threadIdx.x;
    const int lane = tid & 63, wave = tid >> 6;
    const int wr = wave >> 1, wc = wave & 1;
    const int fr = lane & 15, fq = lane >> 4;

    int idx = blockIdx.x;                  // 0..35 triangular
    int tt = (int)((sqrtf(8.f * (float)idx + 1.f) - 1.f) * 0.5f);
    while ((tt + 1) * (tt + 2) / 2 <= idx) ++tt;
    while (tt * (tt + 1) / 2 > idx) --tt;
    const int ss = idx - tt * (tt + 1) / 2;
    const int t0 = tt << 7, s0 = ss << 7;
    const int bh = blockIdx.y;

    const unsigned short* Q = qb + ((size_t)bh << 17);
    const unsigned short* K = kb + ((size_t)bh << 17);

    f32x4 acc[4][4];
#pragma unroll
    for (int i = 0; i < 4; ++i)
#pragma unroll
        for (int j = 0; j < 4; ++j) acc[i][j] = (f32x4){0.f, 0.f, 0.f, 0.f};

    for (int k0 = 0; k0 < 128; k0 += 32) {
#pragma unroll
        for (int i = 0; i < 2; ++i) {
            int c = i * 256 + tid;
            int r = c >> 2, kc = c & 3;
            gload16(Q + (size_t)(t0 + r) * 128 + k0 + kc * 8, &lA[c * 8]);
        }
#pragma unroll
        for (int i = 0; i < 2; ++i) {
            int c = i * 256 + tid;
            int r = c >> 2, kc = c & 3;
            gload16(K + (size_t)(s0 + r) * 128 + k0 + kc * 8, &lB[c * 8]);
        }
        __syncthreads();

        short8 afr[4], bfr[4];
#pragma unroll
        for (int mi = 0; mi < 4; ++mi)
            afr[mi] = *(const short8*)&lA[(wr * 64 + mi * 16 + fr) * 32 + fq * 8];
#pragma unroll
        for (int ni = 0; ni < 4; ++ni)
            bfr[ni] = *(const short8*)&lB[(wc * 64 + ni * 16 + fr) * 32 + fq * 8];
#pragma unroll
        for (int mi = 0; mi < 4; ++mi)
#pragma unroll
            for (int ni = 0; ni < 4; ++ni)
                acc[mi][ni] = __builtin_amdgcn_mfma_f32_16x16x32_bf16(
                    afr[mi], bfr[ni], acc[mi][ni], 0, 0, 0);
        __syncthreads();
    }

    // ---- slab-transposed epilogue: 4 slabs of 32 rows ----
    unsigned short* EO = ebuf + ((size_t)bh << 20);
    const float* RLb = rel + ((size_t)bh << 20);
#pragma unroll
    for (int sl = 0; sl < 4; ++sl) {
        if (wr == (sl >> 1)) {
#pragma unroll
            for (int mi2 = 0; mi2 < 2; ++mi2) {
                int mi = ((sl & 1) << 1) + mi2;
#pragma unroll
                for (int ni = 0; ni < 4; ++ni)
#pragma unroll
                    for (int r = 0; r < 4; ++r) {
                        int srow = (mi2 << 4) + (fq << 2) + r;
                        int col = (wc << 6) + (ni << 4) + fr;
                        slab[srow * 128 + (col ^ (((srow >> 2) & 3) << 4))] = acc[mi][ni][r];
                    }
            }
        }
        __syncthreads();
        {
            int srow = tid >> 3;
            int tg = t0 + (sl << 5) + srow;
            const float* RL = RLb + ((size_t)tg << 10) + s0;
            unsigned short* ER = EO + ((size_t)tg << 10) + s0;
            float rsum = 0.f;
#pragma unroll
            for (int c = 0; c < 4; ++c) {
                int col = ((tid & 7) << 2) + (c << 5);   // 8 lanes cover contiguous run
                float4 sv = *(const float4*)&slab[srow * 128 + (col ^ (((srow >> 2) & 3) << 4))];
                float4 rl = *(const float4*)(RL + col);
                float4 e;
                e.x = (s0 + col     <= tg) ? __expf(sv.x + rl.x - 15.f) : 0.f;
                e.y = (s0 + col + 1 <= tg) ? __expf(sv.y + rl.y - 15.f) : 0.f;
                e.z = (s0 + col + 2 <= tg) ? __expf(sv.z + rl.z - 15.f) : 0.f;
                e.w = (s0 + col + 3 <= tg) ? __expf(sv.w + rl.w - 15.f) : 0.f;
                ushort4v h;
                h.x = f2bf(e.x); h.y = f2bf(e.y); h.z = f2bf(e.z); h.w = f2bf(e.w);
                *(ushort4v*)(ER + col) = h;
                rsum += e.x + e.y + e.z + e.w;
            }
            rsum += __shfl_xor(rsum, 1);
            rsum += __shfl_xor(rsum, 2);
            rsum += __shfl_xor(rsum, 4);
            if ((tid & 7) == 0)
                psum[((((size_t)bh << 10) + tg) << 3) + ss] = rsum;
        }
        __syncthreads();
    }
}

// ---------------------------------------------------------------------------
// pvw_k: one block per (bh, 64-row t-strip). For each 64-wide s-tile:
//   stage e (bf16, 8KB) + V^T (16KB) swizzled; write final P = e/l (float4,
//   single write of d_out attn region); PV MFMA accumulates O from same LDS.
// O scaled by 1/l at end (diag scale commutes). Zero-fill upper cols.
// 25KB LDS -> ~6 blocks/CU.
// ---------------------------------------------------------------------------
__global__ __launch_bounds__(256)
void pvw_k(const unsigned short* __restrict__ ebuf, const unsigned short* __restrict__ vt,
           const float* __restrict__ psum, float* __restrict__ attnP,
           unsigned short* __restrict__ am) {
    __shared__ alignas(16) unsigned short lE[64 * 64];    // 8KB, 128B rows swizzled
    __shared__ alignas(16) unsigned short lV[128 * 64];   // 16KB, 128B rows swizzled
    __shared__ float lInvF[64];

    const int tid = threadIdx.x;
    const int lane = tid & 63, wave = tid >> 6;
    const int wr = wave >> 1, wc = wave & 1;
    const int fr = lane & 15, fq = lane >> 4;
    const int strip = 15 - blockIdx.x;        // heavy first
    const int t0 = strip << 6;
    const int bh = blockIdx.y;
    const int hh = bh & 15, bb = bh >> 4;
    const int n_s = (t0 >> 6) + 1;            // 64-wide s-tiles covering [0, t0+64)

    const unsigned short* EB = ebuf + ((size_t)bh << 20) + ((size_t)t0 << 10);
    const unsigned short* Vb = vt + ((size_t)bh << 17);
    float* PO = attnP + (((size_t)(hh * BB + bb)) << 20) + ((size_t)t0 << 10);

    if (tid < 64) {
        const float* p = psum + ((((size_t)bh << 10) + t0 + tid) << 3);
        const int tt = t0 >> 7;
        float s = 0.f;
#pragma unroll
        for (int j = 0; j < 8; ++j) s += (j <= tt) ? p[j] : 0.f;
        lInvF[tid] = 1.f / s;
    }
    __syncthreads();

    f32x4 acc[2][4];
#pragma unroll
    for (int i = 0; i < 2; ++i)
#pragma unroll
        for (int j = 0; j < 4; ++j) acc[i][j] = (f32x4){0.f, 0.f, 0.f, 0.f};

    for (int j = 0; j < n_s; ++j) {
        int s0 = j << 6;
        // stage e tile 64x64 bf16 (8KB)
#pragma unroll
        for (int i = 0; i < 2; ++i) {
            int o = (i * 256 + tid) * 16;
            int r = o >> 7;
            int cb = (o & 127) ^ ((r & 7) << 4);
            gload16(EB + (size_t)r * 1024 + s0 + (cb >> 1), (char*)lE + o);
        }
        // stage V^T tile 128x64 bf16 (16KB)
#pragma unroll
        for (int i = 0; i < 4; ++i) {
            int o = (i * 256 + tid) * 16;
            int r = o >> 7;
            int cb = (o & 127) ^ ((r & 7) << 4);
            gload16(Vb + (size_t)r * 1024 + s0 + (cb >> 1), (char*)lV + o);
        }
        __syncthreads();

        // P write: p = e * inv, float4 coalesced (16 cols per thread)
        {
            int row = tid >> 2, col0 = (tid & 3) << 4;
            float inv = lInvF[row];
            float* PR = PO + (size_t)row * 1024 + s0 + col0;
#pragma unroll
            for (int cc = 0; cc < 2; ++cc) {
                int cbyte = ((col0 + cc * 8) * 2) ^ ((row & 7) << 4);
                ushort8v ev = *(const ushort8v*)((const char*)lE + row * 128 + cbyte);
                float4 p0, p1;
                p0.x = bf2f(ev[0]) * inv; p0.y = bf2f(ev[1]) * inv;
                p0.z = bf2f(ev[2]) * inv; p0.w = bf2f(ev[3]) * inv;
                p1.x = bf2f(ev[4]) * inv; p1.y = bf2f(ev[5]) * inv;
                p1.z = bf2f(ev[6]) * inv; p1.w = bf2f(ev[7]) * inv;
                *(float4*)(PR + cc * 8) = p0;
                *(float4*)(PR + cc * 8 + 4) = p1;
            }
        }

        // PV MFMA: O[64t x 128d] += e @ V^T^T, K = 64
#pragma unroll
        for (int ks = 0; ks < 2; ++ks) {
            short8 pf[2], vf[4];
#pragma unroll
            for (int mi = 0; mi < 2; ++mi) {
                int row = wr * 32 + mi * 16 + fr;
                int cb = (ks * 64 + fq * 16) ^ ((row & 7) << 4);
                pf[mi] = *(const short8*)((const char*)lE + row * 128 + cb);
            }
#pragma unroll
            for (int ni = 0; ni < 4; ++ni) {
                int row = wc * 64 + ni * 16 + fr;
                int cb = (ks * 64 + fq * 16) ^ ((row & 7) << 4);
                vf[ni] = *(const short8*)((const char*)lV + row * 128 + cb);
            }
#pragma unroll
            for (int mi = 0; mi < 2; ++mi)
#pragma unroll
                for (int ni = 0; ni < 4; ++ni)
                    acc[mi][ni] = __builtin_amdgcn_mfma_f32_16x16x32_bf16(
                        pf[mi], vf[ni], acc[mi][ni], 0, 0, 0);
        }
        __syncthreads();
    }

    // zero-fill cols [t0+64, 1024)
    {
        int row = tid >> 2;
        float4 z = make_float4(0.f, 0.f, 0.f, 0.f);
        for (int c = (n_s << 6) + ((tid & 3) << 2); c < 1024; c += 16)
            *(float4*)(PO + (size_t)row * 1024 + c) = z;
    }

    // O epilogue: scale by 1/l, write am (B,L,E) bf16
#pragma unroll
    for (int mi = 0; mi < 2; ++mi)
#pragma unroll
        for (int ni = 0; ni < 4; ++ni)
#pragma unroll
            for (int r = 0; r < 4; ++r) {
                int tl = wr * 32 + mi * 16 + fq * 4 + r;
                int d = wc * 64 + ni * 16 + fr;
                float o = acc[mi][ni][r] * lInvF[tl];
                am[(((size_t)(bb * 1024 + t0 + tl)) << 11) + hh * 128 + d] = f2bf(o);
            }
}

// ---------------------------------------------------------------------------
extern "C" void kernel_launch(void* const* d_in, const int* in_sizes, int n_in,
                              void* d_out, int out_size, void* d_ws, size_t ws_size,
                              hipStream_t stream) {
    const float* query = (const float*)d_in[0];
    const float* Wq    = (const float*)d_in[1];
    const float* bq    = (const float*)d_in[2];
    const float* Wk    = (const float*)d_in[3];
    const float* bk    = (const float*)d_in[4];
    const float* Wv    = (const float*)d_in[5];
    const float* bv    = (const float*)d_in[6];
    const float* Wo    = (const float*)d_in[7];
    const float* bo    = (const float*)d_in[8];
    const float* rel   = (const float*)d_in[10];

    float* out    = (float*)d_out;              // (B, L, E)
    float* attn_w = out + OUT0_ELEMS;           // (H, B, L, L)

    char* w = (char*)d_ws;
    unsigned short* Xbf   = (unsigned short*)(w);               // 16MB  (B*L, E)
    unsigned short* Wqkvb = (unsigned short*)(w + (16 << 20));  // 24MB  (3*E, E)
    unsigned short* Wob   = (unsigned short*)(w + (40 << 20));  // 8MB
    unsigned short* qb    = (unsigned short*)(w + (48 << 20));  // 16MB (BH,L,DH)
    unsigned short* kb    = (unsigned short*)(w + (64 << 20));  // 16MB
    unsigned short* vt    = (unsigned short*)(w + (80 << 20));  // 16MB (BH,DH,L)
    unsigned short* am    = (unsigned short*)(w + (96 << 20));  // 16MB (B,L,E)
    float4* tab           = (float4*)(w + (112 << 20));         // 1MB
    float* psum           = (float*)(w + (113u << 20));         // 2MB (BH,L,8)
    unsigned short* ebuf  = (unsigned short*)(w + (128u << 20)); // 128MB (BH,L,L) bf16

    const float scaling = 0.08838834764831845f; // DH^-0.5

    xpos_table_k<<<LL, 64, 0, stream>>>(tab);

    cvt_k<<<4096, 256, 0, stream>>>(query, Xbf, OUT0_ELEMS);
    cvt_k<<<2048, 256, 0, stream>>>(Wq, Wqkvb, EE * EE);
    cvt_k<<<2048, 256, 0, stream>>>(Wk, Wqkvb + (size_t)EE * EE, EE * EE);
    cvt_k<<<2048, 256, 0, stream>>>(Wv, Wqkvb + 2 * (size_t)EE * EE, EE * EE);
    cvt_k<<<2048, 256, 0, stream>>>(Wo, Wob, EE * EE);

    dim3 gqkv(3 * EE / 128, NTOK / 128);        // (48, 32)
    mmqkv_k<<<gqkv, 256, 0, stream>>>(Xbf, Wqkvb, bq, bk, bv, qb, kb, vt, scaling);

    xpos_apply_k<<<(NBH * LL * 16) / 256, 256, 0, stream>>>(qb, kb, tab);

    dim3 gsc(36, NBH);                          // causal tiles only
    scores_k<<<gsc, 256, 0, stream>>>(qb, kb, rel, ebuf, psum);

    dim3 gpv(16, NBH);                          // 64-row strips, 1024 blocks
    pvw_k<<<gpv, 256, 0, stream>>>(ebuf, vt, psum, attn_w, am);

    dim3 gout(EE / 128, NTOK / 128);            // (16, 32)
    mmo_k<<<gout, 256, 0, stream>>>(am, Wob, bo, out);
}

// Round 7
// 472.021 us; speedup vs baseline: 1.1360x; 1.0201x over previous
//
#include <hip/hip_runtime.h>
#include <math.h>

// (B, L, E, H) = (4, 1024, 2048, 16), DH = 128
#define BB 4
#define LL 1024
#define EE 2048
#define HH 16
#define DHD 128
#define NTOK 4096
#define NBH 64
#define OUT0_ELEMS 8388608     // B*L*E

typedef __attribute__((ext_vector_type(8))) short short8;       // 8 bf16 (MFMA A/B frag)
typedef __attribute__((ext_vector_type(4))) float f32x4;        // MFMA C/D frag
typedef __attribute__((ext_vector_type(4))) unsigned short ushort4v;
typedef __attribute__((ext_vector_type(8))) unsigned short ushort8v;

__device__ __forceinline__ unsigned short f2bf(float x) {
    union { float f; unsigned int u; } v; v.f = x;
    unsigned int r = v.u + 0x7FFFu + ((v.u >> 16) & 1u);   // RNE
    return (unsigned short)(r >> 16);
}
__device__ __forceinline__ float bf2f(unsigned short h) {
    union { unsigned int u; float f; } v; v.u = ((unsigned int)h) << 16;
    return v.f;
}

// async global->LDS, 16B per lane
__device__ __forceinline__ void gload16(const void* g, void* l) {
    __builtin_amdgcn_global_load_lds((const __attribute__((address_space(1))) void*)g,
                                     (__attribute__((address_space(3))) void*)l,
                                     16, 0, 0);
}

// ---------------------------------------------------------------------------
// One-shot fp32 -> bf16 convert of X and all 4 weights (region dispatch).
// Regions: [0,8.4M) X ; then Wq,Wk,Wv (into Wqkvb) ; Wo (into Wob).
// ---------------------------------------------------------------------------
__global__ __launch_bounds__(256)
void cvt_all_k(const float* __restrict__ X, const float* __restrict__ Wq,
               const float* __restrict__ Wk, const float* __restrict__ Wv,
               const float* __restrict__ Wo, unsigned short* __restrict__ Xbf,
               unsigned short* __restrict__ Wqkvb, unsigned short* __restrict__ Wob) {
    size_t g = (size_t)(blockIdx.x * 256 + threadIdx.x) * 8;
    if (g >= 25165824u) return;
    const float* src;
    unsigned short* dst;
    if (g < 8388608u) {
        src = X + g; dst = Xbf + g;
    } else {
        size_t rr = g - 8388608u;
        int wi = (int)(rr >> 22);
        size_t o = rr & 4194303u;
        src = (wi == 0 ? Wq : wi == 1 ? Wk : wi == 2 ? Wv : Wo) + o;
        dst = (wi < 3 ? Wqkvb + ((size_t)wi << 22) : Wob) + o;
    }
    float4 a = *(const float4*)(src);
    float4 b = *(const float4*)(src + 4);
    ushort4v u, w;
    u.x = f2bf(a.x); u.y = f2bf(a.y); u.z = f2bf(a.z); u.w = f2bf(a.w);
    w.x = f2bf(b.x); w.y = f2bf(b.y); w.z = f2bf(b.z); w.w = f2bf(b.w);
    *(ushort4v*)(dst) = u;
    *(ushort4v*)(dst + 4) = w;
}

// ---------------------------------------------------------------------------
// xPos table: per (t, j), j in [0,64): {cos*sc, sin*sc, cos/sc, sin/sc}
// ---------------------------------------------------------------------------
__global__ __launch_bounds__(64) void xpos_table_k(float4* __restrict__ tab) {
    int t = blockIdx.x;
    int j = threadIdx.x;
    float pos = (float)(t - 512);
    float base = (2.0f * (float)j + 51.2f) * (1.0f / 179.2f);
    float sc = powf(base, pos * (1.0f / 512.0f));
    float inv_freq = powf(10000.0f, -(float)j * (1.0f / 64.0f));
    float ang = (float)t * inv_freq;
    float s = sinf(ang);
    float c = cosf(ang);
    tab[(t << 6) | j] = make_float4(c * sc, s * sc, c / sc, s / sc);
}

// ---------------------------------------------------------------------------
// Combined QKV projection GEMM with FUSED xPos rotation in the epilogue.
// C = X @ [Wq;Wk;Wv]^T, N = 6144; w = n0>>11 selects q/k/v.
//   w=0 -> qb bf16 split (BH,L,DH), *scaling, xPos(scale)
//   w=1 -> kb bf16 split, xPos(1/scale)
//   w=2 -> vt bf16 transposed (BH,DH,L)
// Rotation pairs (2j,2j+1) live in lanes fr^1 -> one __shfl_xor.
// ---------------------------------------------------------------------------
__global__ __launch_bounds__(256)
void mmqkv_k(const unsigned short* __restrict__ Abf, const unsigned short* __restrict__ Wqkv,
             const float* __restrict__ bq, const float* __restrict__ bk,
             const float* __restrict__ bv, unsigned short* __restrict__ qb,
             unsigned short* __restrict__ kb, unsigned short* __restrict__ vt,
             const float4* __restrict__ tab, float scaling) {
    __shared__ alignas(16) unsigned short lA[128 * 32];
    __shared__ alignas(16) unsigned short lB[128 * 32];

    const int tid = threadIdx.x;
    const int lane = tid & 63;
    const int wave = tid >> 6;
    const int wr = wave >> 1, wc = wave & 1;
    const int fr = lane & 15, fq = lane >> 4;
    const int m0 = blockIdx.y * 128, n0 = blockIdx.x * 128;
    const int w = n0 >> 11;                       // 0=q, 1=k, 2=v
    const float* bsel = (w == 0) ? bq : (w == 1) ? bk : bv;
    const float alpha = (w == 0) ? scaling : 1.0f;

    f32x4 acc[4][4];
#pragma unroll
    for (int i = 0; i < 4; ++i)
#pragma unroll
        for (int j = 0; j < 4; ++j) acc[i][j] = (f32x4){0.f, 0.f, 0.f, 0.f};

    for (int k0 = 0; k0 < 2048; k0 += 32) {
#pragma unroll
        for (int i = 0; i < 2; ++i) {
            int c = i * 256 + tid;
            int r = c >> 2, kc = c & 3;
            gload16(Abf + (size_t)(m0 + r) * 2048 + k0 + kc * 8, &lA[c * 8]);
        }
#pragma unroll
        for (int i = 0; i < 2; ++i) {
            int c = i * 256 + tid;
            int r = c >> 2, kc = c & 3;
            gload16(Wqkv + (size_t)(n0 + r) * 2048 + k0 + kc * 8, &lB[c * 8]);
        }
        __syncthreads();

        short8 afr[4], bfr[4];
#pragma unroll
        for (int mi = 0; mi < 4; ++mi)
            afr[mi] = *(const short8*)&lA[(wr * 64 + mi * 16 + fr) * 32 + fq * 8];
#pragma unroll
        for (int ni = 0; ni < 4; ++ni)
            bfr[ni] = *(const short8*)&lB[(wc * 64 + ni * 16 + fr) * 32 + fq * 8];
#pragma unroll
        for (int mi = 0; mi < 4; ++mi)
#pragma unroll
            for (int ni = 0; ni < 4; ++ni)
                acc[mi][ni] = __builtin_amdgcn_mfma_f32_16x16x32_bf16(
                    afr[mi], bfr[ni], acc[mi][ni], 0, 0, 0);
        __syncthreads();
    }

#pragma unroll
    for (int mi = 0; mi < 4; ++mi) {
#pragma unroll
        for (int ni = 0; ni < 4; ++ni) {
            int n = n0 + wc * 64 + ni * 16 + fr;
            int nn = n & 2047;
            int h = nn >> 7, d = nn & 127;
            float bias = bsel[nn];
#pragma unroll
            for (int r = 0; r < 4; ++r) {
                int m = m0 + wr * 64 + mi * 16 + fq * 4 + r;
                int b_ = m >> 10, t = m & 1023;
                float v = alpha * (acc[mi][ni][r] + bias);
                if (w < 2) {
                    // fused xPos rotation: partner element d^1 is in lane fr^1
                    float pv = __shfl_xor(v, 1);
                    float4 tb = tab[(t << 6) | (d >> 1)];
                    float c = (w == 0) ? tb.x : tb.z;
                    float s = (w == 0) ? tb.y : tb.w;
                    float rot = (d & 1) ? (v * c + pv * s) : (v * c - pv * s);
                    unsigned short* dst = (w == 0) ? qb : kb;
                    dst[(((size_t)(b_ * HH + h) << 10 | t) << 7) | d] = f2bf(rot);
                } else {
                    vt[((size_t)((b_ * HH + h) * 128 + d) << 10) | t] = f2bf(v);
                }
            }
        }
    }
}

// ---------------------------------------------------------------------------
// Output projection GEMM: out = am @ Wo^T + bo, fp32 (B,L,E)
// ---------------------------------------------------------------------------
__global__ __launch_bounds__(256)
void mmo_k(const unsigned short* __restrict__ Abf, const unsigned short* __restrict__ Bp,
           const float* __restrict__ bias, float* __restrict__ C) {
    __shared__ alignas(16) unsigned short lA[128 * 32];
    __shared__ alignas(16) unsigned short lB[128 * 32];

    const int tid = threadIdx.x;
    const int lane = tid & 63;
    const int wave = tid >> 6;
    const int wr = wave >> 1, wc = wave & 1;
    const int fr = lane & 15, fq = lane >> 4;
    const int m0 = blockIdx.y * 128, n0 = blockIdx.x * 128;

    f32x4 acc[4][4];
#pragma unroll
    for (int i = 0; i < 4; ++i)
#pragma unroll
        for (int j = 0; j < 4; ++j) acc[i][j] = (f32x4){0.f, 0.f, 0.f, 0.f};

    for (int k0 = 0; k0 < 2048; k0 += 32) {
#pragma unroll
        for (int i = 0; i < 2; ++i) {
            int c = i * 256 + tid;
            int r = c >> 2, kc = c & 3;
            gload16(Abf + (size_t)(m0 + r) * 2048 + k0 + kc * 8, &lA[c * 8]);
        }
#pragma unroll
        for (int i = 0; i < 2; ++i) {
            int c = i * 256 + tid;
            int r = c >> 2, kc = c & 3;
            gload16(Bp + (size_t)(n0 + r) * 2048 + k0 + kc * 8, &lB[c * 8]);
        }
        __syncthreads();

        short8 afr[4], bfr[4];
#pragma unroll
        for (int mi = 0; mi < 4; ++mi)
            afr[mi] = *(const short8*)&lA[(wr * 64 + mi * 16 + fr) * 32 + fq * 8];
#pragma unroll
        for (int ni = 0; ni < 4; ++ni)
            bfr[ni] = *(const short8*)&lB[(wc * 64 + ni * 16 + fr) * 32 + fq * 8];
#pragma unroll
        for (int mi = 0; mi < 4; ++mi)
#pragma unroll
            for (int ni = 0; ni < 4; ++ni)
                acc[mi][ni] = __builtin_amdgcn_mfma_f32_16x16x32_bf16(
                    afr[mi], bfr[ni], acc[mi][ni], 0, 0, 0);
        __syncthreads();
    }

#pragma unroll
    for (int mi = 0; mi < 4; ++mi)
#pragma unroll
        for (int ni = 0; ni < 4; ++ni)
#pragma unroll
            for (int r = 0; r < 4; ++r) {
                int m = m0 + wr * 64 + mi * 16 + fq * 4 + r;
                int n = n0 + wc * 64 + ni * 16 + fr;
                C[(size_t)m * EE + n] = acc[mi][ni][r] + bias[n];
            }
}

// ---------------------------------------------------------------------------
// scores_k: one block per causal 128x128 tile (tt, ss<=tt, bh).
// S = q@k^T (K=128 MFMA), slab-transposed epilogue:
//   e = exp(S + rel - 15)   (causal-masked)
// e written BF16 (unnormalized) into ws ebuf[bh][t][s]; per-row partial
// sums into psum[bh][t][ss]. Epilogue I/O coalesced.
// ---------------------------------------------------------------------------
__global__ __launch_bounds__(256)
void scores_k(const unsigned short* __restrict__ qb, const unsigned short* __restrict__ kb,
              const float* __restrict__ rel, unsigned short* __restrict__ ebuf,
              float* __restrict__ psum) {
    __shared__ alignas(16) char smem[16384];
    unsigned short* lA = (unsigned short*)smem;           // 128x32 bf16
    unsigned short* lB = (unsigned short*)(smem + 8192);  // 128x32 bf16
    float* slab = (float*)smem;                           // 32x128 f32 (epilogue reuse)

    const int tid = threadIdx.x;
    const int lane = tid & 63, wave = tid >> 6;
    const int wr = wave >> 1, wc = wave & 1;
    const int fr = lane & 15, fq = lane >> 4;

    int idx = blockIdx.x;                  // 0..35 triangular
    int tt = (int)((sqrtf(8.f * (float)idx + 1.f) - 1.f) * 0.5f);
    while ((tt + 1) * (tt + 2) / 2 <= idx) ++tt;
    while (tt * (tt + 1) / 2 > idx) --tt;
    const int ss = idx - tt * (tt + 1) / 2;
    const int t0 = tt << 7, s0 = ss << 7;
    const int bh = blockIdx.y;

    const unsigned short* Q = qb + ((size_t)bh << 17);
    const unsigned short* K = kb + ((size_t)bh << 17);

    f32x4 acc[4][4];
#pragma unroll
    for (int i = 0; i < 4; ++i)
#pragma unroll
        for (int j = 0; j < 4; ++j) acc[i][j] = (f32x4){0.f, 0.f, 0.f, 0.f};

    for (int k0 = 0; k0 < 128; k0 += 32) {
#pragma unroll
        for (int i = 0; i < 2; ++i) {
            int c = i * 256 + tid;
            int r = c >> 2, kc = c & 3;
            gload16(Q + (size_t)(t0 + r) * 128 + k0 + kc * 8, &lA[c * 8]);
        }
#pragma unroll
        for (int i = 0; i < 2; ++i) {
            int c = i * 256 + tid;
            int r = c >> 2, kc = c & 3;
            gload16(K + (size_t)(s0 + r) * 128 + k0 + kc * 8, &lB[c * 8]);
        }
        __syncthreads();

        short8 afr[4], bfr[4];
#pragma unroll
        for (int mi = 0; mi < 4; ++mi)
            afr[mi] = *(const short8*)&lA[(wr * 64 + mi * 16 + fr) * 32 + fq * 8];
#pragma unroll
        for (int ni = 0; ni < 4; ++ni)
            bfr[ni] = *(const short8*)&lB[(wc * 64 + ni * 16 + fr) * 32 + fq * 8];
#pragma unroll
        for (int mi = 0; mi < 4; ++mi)
#pragma unroll
            for (int ni = 0; ni < 4; ++ni)
                acc[mi][ni] = __builtin_amdgcn_mfma_f32_16x16x32_bf16(
                    afr[mi], bfr[ni], acc[mi][ni], 0, 0, 0);
        __syncthreads();
    }

    // ---- slab-transposed epilogue: 4 slabs of 32 rows ----
    unsigned short* EO = ebuf + ((size_t)bh << 20);
    const float* RLb = rel + ((size_t)bh << 20);
#pragma unroll
    for (int sl = 0; sl < 4; ++sl) {
        if (wr == (sl >> 1)) {
#pragma unroll
            for (int mi2 = 0; mi2 < 2; ++mi2) {
                int mi = ((sl & 1) << 1) + mi2;
#pragma unroll
                for (int ni = 0; ni < 4; ++ni)
#pragma unroll
                    for (int r = 0; r < 4; ++r) {
                        int srow = (mi2 << 4) + (fq << 2) + r;
                        int col = (wc << 6) + (ni << 4) + fr;
                        slab[srow * 128 + (col ^ (((srow >> 2) & 3) << 4))] = acc[mi][ni][r];
                    }
            }
        }
        __syncthreads();
        {
            int srow = tid >> 3;
            int tg = t0 + (sl << 5) + srow;
            const float* RL = RLb + ((size_t)tg << 10) + s0;
            unsigned short* ER = EO + ((size_t)tg << 10) + s0;
            float rsum = 0.f;
#pragma unroll
            for (int c = 0; c < 4; ++c) {
                int col = ((tid & 7) << 2) + (c << 5);   // 8 lanes cover contiguous run
                float4 sv = *(const float4*)&slab[srow * 128 + (col ^ (((srow >> 2) & 3) << 4))];
                float4 rl = *(const float4*)(RL + col);
                float4 e;
                e.x = (s0 + col     <= tg) ? __expf(sv.x + rl.x - 15.f) : 0.f;
                e.y = (s0 + col + 1 <= tg) ? __expf(sv.y + rl.y - 15.f) : 0.f;
                e.z = (s0 + col + 2 <= tg) ? __expf(sv.z + rl.z - 15.f) : 0.f;
                e.w = (s0 + col + 3 <= tg) ? __expf(sv.w + rl.w - 15.f) : 0.f;
                ushort4v h;
                h.x = f2bf(e.x); h.y = f2bf(e.y); h.z = f2bf(e.z); h.w = f2bf(e.w);
                *(ushort4v*)(ER + col) = h;
                rsum += e.x + e.y + e.z + e.w;
            }
            rsum += __shfl_xor(rsum, 1);
            rsum += __shfl_xor(rsum, 2);
            rsum += __shfl_xor(rsum, 4);
            if ((tid & 7) == 0)
                psum[((((size_t)bh << 10) + tg) << 3) + ss] = rsum;
        }
        __syncthreads();
    }
}

// ---------------------------------------------------------------------------
// pvw_k: one block per (bh, 64-row t-strip). For each 64-wide s-tile:
//   stage e (bf16, 8KB) + V^T (16KB) swizzled; write final P = e/l (float4,
//   single write of d_out attn region); PV MFMA accumulates O from same LDS.
// O scaled by 1/l at end. Zero-fill upper cols. 25KB LDS -> ~6 blocks/CU.
// Grid (bh, strip): heaviest strips of ALL bh dispatch first.
// ---------------------------------------------------------------------------
__global__ __launch_bounds__(256)
void pvw_k(const unsigned short* __restrict__ ebuf, const unsigned short* __restrict__ vt,
           const float* __restrict__ psum, float* __restrict__ attnP,
           unsigned short* __restrict__ am) {
    __shared__ alignas(16) unsigned short lE[64 * 64];    // 8KB, 128B rows swizzled
    __shared__ alignas(16) unsigned short lV[128 * 64];   // 16KB, 128B rows swizzled
    __shared__ float lInvF[64];

    const int tid = threadIdx.x;
    const int lane = tid & 63, wave = tid >> 6;
    const int wr = wave >> 1, wc = wave & 1;
    const int fr = lane & 15, fq = lane >> 4;
    const int strip = 15 - blockIdx.y;        // heavy first
    const int t0 = strip << 6;
    const int bh = blockIdx.x;
    const int hh = bh & 15, bb = bh >> 4;
    const int n_s = (t0 >> 6) + 1;            // 64-wide s-tiles covering [0, t0+64)

    const unsigned short* EB = ebuf + ((size_t)bh << 20) + ((size_t)t0 << 10);
    const unsigned short* Vb = vt + ((size_t)bh << 17);
    float* PO = attnP + (((size_t)(hh * BB + bb)) << 20) + ((size_t)t0 << 10);

    if (tid < 64) {
        const float* p = psum + ((((size_t)bh << 10) + t0 + tid) << 3);
        const int tt = t0 >> 7;
        float s = 0.f;
#pragma unroll
        for (int j = 0; j < 8; ++j) s += (j <= tt) ? p[j] : 0.f;
        lInvF[tid] = 1.f / s;
    }
    __syncthreads();

    f32x4 acc[2][4];
#pragma unroll
    for (int i = 0; i < 2; ++i)
#pragma unroll
        for (int j = 0; j < 4; ++j) acc[i][j] = (f32x4){0.f, 0.f, 0.f, 0.f};

    for (int j = 0; j < n_s; ++j) {
        int s0 = j << 6;
        // stage e tile 64x64 bf16 (8KB)
#pragma unroll
        for (int i = 0; i < 2; ++i) {
            int o = (i * 256 + tid) * 16;
            int r = o >> 7;
            int cb = (o & 127) ^ ((r & 7) << 4);
            gload16(EB + (size_t)r * 1024 + s0 + (cb >> 1), (char*)lE + o);
        }
        // stage V^T tile 128x64 bf16 (16KB)
#pragma unroll
        for (int i = 0; i < 4; ++i) {
            int o = (i * 256 + tid) * 16;
            int r = o >> 7;
            int cb = (o & 127) ^ ((r & 7) << 4);
            gload16(Vb + (size_t)r * 1024 + s0 + (cb >> 1), (char*)lV + o);
        }
        __syncthreads();

        // P write: p = e * inv, float4 coalesced (16 cols per thread)
        {
            int row = tid >> 2, col0 = (tid & 3) << 4;
            float inv = lInvF[row];
            float* PR = PO + (size_t)row * 1024 + s0 + col0;
#pragma unroll
            for (int cc = 0; cc < 2; ++cc) {
                int cbyte = ((col0 + cc * 8) * 2) ^ ((row & 7) << 4);
                ushort8v ev = *(const ushort8v*)((const char*)lE + row * 128 + cbyte);
                float4 p0, p1;
                p0.x = bf2f(ev[0]) * inv; p0.y = bf2f(ev[1]) * inv;
                p0.z = bf2f(ev[2]) * inv; p0.w = bf2f(ev[3]) * inv;
                p1.x = bf2f(ev[4]) * inv; p1.y = bf2f(ev[5]) * inv;
                p1.z = bf2f(ev[6]) * inv; p1.w = bf2f(ev[7]) * inv;
                *(float4*)(PR + cc * 8) = p0;
                *(float4*)(PR + cc * 8 + 4) = p1;
            }
        }

        // PV MFMA: O[64t x 128d] += e @ V^T^T, K = 64
#pragma unroll
        for (int ks = 0; ks < 2; ++ks) {
            short8 pf[2], vf[4];
#pragma unroll
            for (int mi = 0; mi < 2; ++mi) {
                int row = wr * 32 + mi * 16 + fr;
                int cb = (ks * 64 + fq * 16) ^ ((row & 7) << 4);
                pf[mi] = *(const short8*)((const char*)lE + row * 128 + cb);
            }
#pragma unroll
            for (int ni = 0; ni < 4; ++ni) {
                int row = wc * 64 + ni * 16 + fr;
                int cb = (ks * 64 + fq * 16) ^ ((row & 7) << 4);
                vf[ni] = *(const short8*)((const char*)lV + row * 128 + cb);
            }
#pragma unroll
            for (int mi = 0; mi < 2; ++mi)
#pragma unroll
                for (int ni = 0; ni < 4; ++ni)
                    acc[mi][ni] = __builtin_amdgcn_mfma_f32_16x16x32_bf16(
                        pf[mi], vf[ni], acc[mi][ni], 0, 0, 0);
        }
        __syncthreads();
    }

    // zero-fill cols [t0+64, 1024)
    {
        int row = tid >> 2;
        float4 z = make_float4(0.f, 0.f, 0.f, 0.f);
        for (int c = (n_s << 6) + ((tid & 3) << 2); c < 1024; c += 16)
            *(float4*)(PO + (size_t)row * 1024 + c) = z;
    }

    // O epilogue: scale by 1/l, write am (B,L,E) bf16
#pragma unroll
    for (int mi = 0; mi < 2; ++mi)
#pragma unroll
        for (int ni = 0; ni < 4; ++ni)
#pragma unroll
            for (int r = 0; r < 4; ++r) {
                int tl = wr * 32 + mi * 16 + fq * 4 + r;
                int d = wc * 64 + ni * 16 + fr;
                float o = acc[mi][ni][r] * lInvF[tl];
                am[(((size_t)(bb * 1024 + t0 + tl)) << 11) + hh * 128 + d] = f2bf(o);
            }
}

// ---------------------------------------------------------------------------
extern "C" void kernel_launch(void* const* d_in, const int* in_sizes, int n_in,
                              void* d_out, int out_size, void* d_ws, size_t ws_size,
                              hipStream_t stream) {
    const float* query = (const float*)d_in[0];
    const float* Wq    = (const float*)d_in[1];
    const float* bq    = (const float*)d_in[2];
    const float* Wk    = (const float*)d_in[3];
    const float* bk    = (const float*)d_in[4];
    const float* Wv    = (const float*)d_in[5];
    const float* bv    = (const float*)d_in[6];
    const float* Wo    = (const float*)d_in[7];
    const float* bo    = (const float*)d_in[8];
    const float* rel   = (const float*)d_in[10];

    float* out    = (float*)d_out;              // (B, L, E)
    float* attn_w = out + OUT0_ELEMS;           // (H, B, L, L)

    char* w = (char*)d_ws;
    unsigned short* Xbf   = (unsigned short*)(w);               // 16MB  (B*L, E)
    unsigned short* Wqkvb = (unsigned short*)(w + (16 << 20));  // 24MB  (3*E, E)
    unsigned short* Wob   = (unsigned short*)(w + (40 << 20));  // 8MB
    unsigned short* qb    = (unsigned short*)(w + (48 << 20));  // 16MB (BH,L,DH)
    unsigned short* kb    = (unsigned short*)(w + (64 << 20));  // 16MB
    unsigned short* vt    = (unsigned short*)(w + (80 << 20));  // 16MB (BH,DH,L)
    unsigned short* am    = (unsigned short*)(w + (96 << 20));  // 16MB (B,L,E)
    float4* tab           = (float4*)(w + (112 << 20));         // 1MB
    float* psum           = (float*)(w + (113u << 20));         // 2MB (BH,L,8)
    unsigned short* ebuf  = (unsigned short*)(w + (128u << 20)); // 128MB (BH,L,L) bf16

    const float scaling = 0.08838834764831845f; // DH^-0.5

    xpos_table_k<<<LL, 64, 0, stream>>>(tab);

    cvt_all_k<<<12288, 256, 0, stream>>>(query, Wq, Wk, Wv, Wo, Xbf, Wqkvb, Wob);

    dim3 gqkv(3 * EE / 128, NTOK / 128);        // (48, 32)
    mmqkv_k<<<gqkv, 256, 0, stream>>>(Xbf, Wqkvb, bq, bk, bv, qb, kb, vt, tab, scaling);

    dim3 gsc(36, NBH);                          // causal tiles only
    scores_k<<<gsc, 256, 0, stream>>>(qb, kb, rel, ebuf, psum);

    dim3 gpv(NBH, 16);                          // (bh, strip) heavy-first
    pvw_k<<<gpv, 256, 0, stream>>>(ebuf, vt, psum, attn_w, am);

    dim3 gout(EE / 128, NTOK / 128);            // (16, 32)
    mmo_k<<<gout, 256, 0, stream>>>(am, Wob, bo, out);
}